// Round 3
// baseline (24.122 us; speedup 1.0000x reference)
//
#include <hip/hip_runtime.h>

#define NB 4
#define NGRID 512
#define NTARGET 512
#define NBASIS 8
#define NCH 8

#if defined(__has_builtin)
#if __has_builtin(__builtin_amdgcn_exp2f)
#define EXP2F(x) __builtin_amdgcn_exp2f(x)
#else
#define EXP2F(x) exp2f(x)
#endif
#else
#define EXP2F(x) exp2f(x)
#endif

// Grid: NB * (NTARGET/8) = 256 blocks, 512 threads = 8 waves.
// Wave w owns target t = tile*8 + w. Lanes = (gs = l>>3, c = l&7).
__global__ __launch_bounds__(512) void final_layer_kernel(
    const float* __restrict__ x_grid,    // (B, G, C)
    const float* __restrict__ h_grid,    // (B, G, K, C)
    const float* __restrict__ target_x,  // (B, T, C)
    const float* __restrict__ W,         // (1, K)
    const float* __restrict__ bias,      // (1,)
    const float* __restrict__ sigma,     // (K, C)
    float* __restrict__ out)             // (B, T, C)
{
    __shared__ float hw[NGRID * NCH];    // 16 KB: hw[g*8+c] = sum_k W[k]*h[b,g,k,c]

    const int tid = threadIdx.x;
    const int l   = tid & 63;
    const int w   = tid >> 6;     // wave 0..7
    const int k   = l >> 3;
    const int c   = l & 7;

    const int bi = blockIdx.x;
    const int b  = bi >> 6;               // 64 target-tiles per batch
    const int t  = (bi & 63) * 8 + w;     // this wave's target

    const float LOG2E = 1.4426950408889634f;

    float sg = sigma[l];          // sigma[k][c]
    float s0 = sigma[c];          // sigma[0][c]
    // uniform lengthscales across k (true for this benchmark's init)?
    bool uniform = __all(sg == s0);

    float tx = target_x[((size_t)b * NTARGET + t) * NCH + c];
    float b0 = bias[0];

    const float* hb = h_grid + (size_t)b * NGRID * (NBASIS * NCH);
    const float* xb = x_grid + (size_t)b * NGRID * NCH;

    if (uniform) {
        // ---- fast path: wt is k-independent; fold W into h first ----
        float wk = W[k];
        // stage hw: wave w covers g in [w*64, w*64+64)
#pragma unroll 8
        for (int g = w * 64; g < w * 64 + 64; ++g) {
            float v = hb[(size_t)g * 64 + l] * wk;   // coalesced 256B/wave
            v += __shfl_xor(v, 8);
            v += __shfl_xor(v, 16);
            v += __shfl_xor(v, 32);                  // sum over k
            if (l < 8) hw[g * 8 + l] = v;
        }
        __syncthreads();

        float scale = __expf(s0) + 1e-6f;
        float coef2 = -0.5f * LOG2E / (scale * scale);

        float a0 = 0.f, a1 = 0.f, a2 = 0.f, a3 = 0.f;
#pragma unroll 4
        for (int j = 0; j < 64; j += 4) {
            // lane l handles g = gs + 8*(j+i): flat addr = 64*(j+i) + l (coalesced)
            float x0 = xb[64 * (j + 0) + l], h0 = hw[64 * (j + 0) + l];
            float x1 = xb[64 * (j + 1) + l], h1 = hw[64 * (j + 1) + l];
            float x2 = xb[64 * (j + 2) + l], h2 = hw[64 * (j + 2) + l];
            float x3 = xb[64 * (j + 3) + l], h3 = hw[64 * (j + 3) + l];
            float d0 = x0 - tx, d1 = x1 - tx, d2 = x2 - tx, d3 = x3 - tx;
            a0 = fmaf(h0, EXP2F(coef2 * (d0 * d0)), a0);
            a1 = fmaf(h1, EXP2F(coef2 * (d1 * d1)), a1);
            a2 = fmaf(h2, EXP2F(coef2 * (d2 * d2)), a2);
            a3 = fmaf(h3, EXP2F(coef2 * (d3 * d3)), a3);
        }
        float v = (a0 + a1) + (a2 + a3);
        v += __shfl_xor(v, 8);
        v += __shfl_xor(v, 16);
        v += __shfl_xor(v, 32);                      // sum over gs
        if (l < 8)
            out[((size_t)b * NTARGET + t) * NCH + l] = v + b0;
    } else {
        // ---- general fallback: per-(k,c) lengthscales ----
        float scale = __expf(sg) + 1e-6f;
        float coef2 = -0.5f * LOG2E / (scale * scale);
        float wk = W[k];
        float acc = 0.f;
#pragma unroll 8
        for (int g = 0; g < NGRID; ++g) {
            float hv = hb[(size_t)g * 64 + l];       // coalesced
            float xg = xb[g * 8 + c];                // broadcast (8 addrs)
            float d  = xg - tx;
            acc = fmaf(hv, EXP2F(coef2 * (d * d)), acc);
        }
        acc *= wk;
        acc += __shfl_xor(acc, 8);
        acc += __shfl_xor(acc, 16);
        acc += __shfl_xor(acc, 32);                  // sum over k
        if (l < 8)
            out[((size_t)b * NTARGET + t) * NCH + l] = acc + b0;
    }
}

extern "C" void kernel_launch(void* const* d_in, const int* in_sizes, int n_in,
                              void* d_out, int out_size, void* d_ws, size_t ws_size,
                              hipStream_t stream) {
    const float* x_grid   = (const float*)d_in[0];
    const float* h_grid   = (const float*)d_in[1];
    const float* target_x = (const float*)d_in[2];
    const float* W        = (const float*)d_in[3];
    const float* bias     = (const float*)d_in[4];
    const float* sigma    = (const float*)d_in[5];
    float* out = (float*)d_out;

    dim3 grid(NB * (NTARGET / 8));   // 256 blocks
    dim3 block(512);                 // 8 waves
    final_layer_kernel<<<grid, block, 0, stream>>>(x_grid, h_grid, target_x,
                                                   W, bias, sigma, out);
}

// Round 4
// 13.970 us; speedup vs baseline: 1.7267x; 1.7267x over previous
//
#include <hip/hip_runtime.h>

#define NB 4
#define NGRID 512
#define NTARGET 512
#define NBASIS 8
#define NCH 8

#if defined(__has_builtin)
#if __has_builtin(__builtin_amdgcn_exp2f)
#define EXP2F(x) __builtin_amdgcn_exp2f(x)
#else
#define EXP2F(x) exp2f(x)
#endif
#else
#define EXP2F(x) exp2f(x)
#endif

// ---------------- Kernel A: hw[b,g,c] = sum_k W[k] * h[b,g,k,c] ----------------
// 16384 outputs, one thread each. 64 blocks x 256 threads. No shuffles.
__global__ __launch_bounds__(256) void hw_kernel(
    const float* __restrict__ h_grid,  // (B, G, K, C)
    const float* __restrict__ W,       // (1, K)
    float* __restrict__ hw)            // (B, G, C) flat
{
    int tid = blockIdx.x * 256 + threadIdx.x;       // 0..16383
    int c = tid & 7;
    int g = (tid >> 3) & (NGRID - 1);
    int b = tid >> 12;
    const float* hp = h_grid + (size_t)b * NGRID * 64 + (size_t)g * 64 + c;
    float acc = 0.0f;
#pragma unroll
    for (int k = 0; k < NBASIS; ++k)
        acc = fmaf(W[k], hp[k * 8], acc);
    hw[tid] = acc;
}

// ---------------- Kernel B: out[b,t,c] = bias + sum_g hw * exp(...) ------------
// 512 blocks x 512 threads (8 waves). Block = (b, 4-target tile).
// Wave w: target = tile*4 + (w>>1), g-half = w&1. Lane: gs = l>>3, c = l&7.
__global__ __launch_bounds__(512) void out_kernel(
    const float* __restrict__ x_grid,    // (B, G, C)
    const float* __restrict__ h_grid,    // (B, G, K, C)  (fallback only)
    const float* __restrict__ hw,        // (B, G, C) from kernel A
    const float* __restrict__ target_x,  // (B, T, C)
    const float* __restrict__ W,         // (1, K)
    const float* __restrict__ bias,      // (1,)
    const float* __restrict__ sigma,     // (K, C)
    float* __restrict__ out)             // (B, T, C)
{
    __shared__ float lds[8 * 8];   // [wave][c]

    const int tid = threadIdx.x;
    const int l   = tid & 63;
    const int w   = tid >> 6;        // 0..7
    const int c   = l & 7;

    const int bi   = blockIdx.x;
    const int b    = bi >> 7;        // 128 tiles per batch
    const int tt   = (bi & 127) * 4; // first target of tile
    const int tl   = w >> 1;         // local target 0..3
    const int t    = tt + tl;
    const int half = w & 1;          // g-half 0/1

    const float LOG2E = 1.4426950408889634f;

    float sg = sigma[l];             // sigma[k][c] for lane's (k,c) view
    float s0 = sigma[c];             // sigma[0][c]
    bool uniform = __all(sg == s0);  // lengthscales uniform across k?

    float tx = target_x[((size_t)b * NTARGET + t) * NCH + c];

    const size_t bbase = (size_t)b * NGRID * NCH + (size_t)half * (NGRID / 2) * NCH;
    const float* xb  = x_grid + bbase;
    const float* hwb = hw + bbase;

    float v;
    if (uniform) {
        float scale = __expf(s0) + 1e-6f;
        float coef2 = -0.5f * LOG2E / (scale * scale);
        float a0 = 0.f, a1 = 0.f, a2 = 0.f, a3 = 0.f;
#pragma unroll
        for (int j = 0; j < 32; j += 4) {
            // flat addr 64*j + l: fully coalesced 256B per wave-instr
            float x0 = xb[64 * (j + 0) + l], h0 = hwb[64 * (j + 0) + l];
            float x1 = xb[64 * (j + 1) + l], h1 = hwb[64 * (j + 1) + l];
            float x2 = xb[64 * (j + 2) + l], h2 = hwb[64 * (j + 2) + l];
            float x3 = xb[64 * (j + 3) + l], h3 = hwb[64 * (j + 3) + l];
            float d0 = x0 - tx, d1 = x1 - tx, d2 = x2 - tx, d3 = x3 - tx;
            a0 = fmaf(h0, EXP2F(coef2 * (d0 * d0)), a0);
            a1 = fmaf(h1, EXP2F(coef2 * (d1 * d1)), a1);
            a2 = fmaf(h2, EXP2F(coef2 * (d2 * d2)), a2);
            a3 = fmaf(h3, EXP2F(coef2 * (d3 * d3)), a3);
        }
        v = (a0 + a1) + (a2 + a3);
    } else {
        // general path: per-(k,c) lengthscales; read h_grid directly
        float coef2k[NBASIS], wv[NBASIS];
#pragma unroll
        for (int k = 0; k < NBASIS; ++k) {
            float s = __expf(sigma[k * 8 + c]) + 1e-6f;
            coef2k[k] = -0.5f * LOG2E / (s * s);
            wv[k] = W[k];
        }
        const int gs = l >> 3;
        const float* hb = h_grid + (size_t)b * NGRID * 64 + (size_t)half * (NGRID / 2) * 64;
        float acc = 0.f;
        for (int j = 0; j < 32; ++j) {
            int g = j * 8 + gs;
            float xg = xb[g * 8 + c];
            float d  = xg - tx;
            float d2 = d * d;
#pragma unroll
            for (int k = 0; k < NBASIS; ++k) {
                float hv = hb[(size_t)g * 64 + k * 8 + c];
                acc = fmaf(wv[k] * hv, EXP2F(coef2k[k] * d2), acc);
            }
        }
        v = acc;
    }

    // reduce over gs (lane bits 3..5) — 3 shuffles ONCE per wave
    v += __shfl_xor(v, 8);
    v += __shfl_xor(v, 16);
    v += __shfl_xor(v, 32);
    if (l < 8) lds[w * 8 + l] = v;
    __syncthreads();

    // combine the two g-halves: 32 threads produce 4 targets x 8 channels
    if (tid < 32) {
        int tl2 = tid >> 3, cc = tid & 7;
        float r = lds[tl2 * 16 + cc] + lds[tl2 * 16 + 8 + cc] + bias[0];
        out[((size_t)b * NTARGET + (tt + tl2)) * NCH + cc] = r;
    }
}

extern "C" void kernel_launch(void* const* d_in, const int* in_sizes, int n_in,
                              void* d_out, int out_size, void* d_ws, size_t ws_size,
                              hipStream_t stream) {
    const float* x_grid   = (const float*)d_in[0];
    const float* h_grid   = (const float*)d_in[1];
    const float* target_x = (const float*)d_in[2];
    const float* W        = (const float*)d_in[3];
    const float* bias     = (const float*)d_in[4];
    const float* sigma    = (const float*)d_in[5];
    float* out = (float*)d_out;
    float* hw  = (float*)d_ws;   // 16384 floats = 64 KB scratch

    hw_kernel<<<dim3(NB * NGRID * NCH / 256), dim3(256), 0, stream>>>(h_grid, W, hw);
    out_kernel<<<dim3(NB * (NTARGET / 4)), dim3(512), 0, stream>>>(
        x_grid, h_grid, hw, target_x, W, bias, sigma, out);
}

// Round 5
// 11.572 us; speedup vs baseline: 2.0845x; 1.2072x over previous
//
#include <hip/hip_runtime.h>

#define NB 4
#define NGRID 512
#define NTARGET 512
#define NBASIS 8
#define NCH 8

#if defined(__has_builtin)
#if __has_builtin(__builtin_amdgcn_exp2f)
#define EXP2F(x) __builtin_amdgcn_exp2f(x)
#else
#define EXP2F(x) exp2f(x)
#endif
#else
#define EXP2F(x) exp2f(x)
#endif

// Single fused kernel. 512 blocks x 512 threads (8 waves).
// Block = (b, 4-target tile). Wave w: target = tile*4 + (w>>1), g-half = w&1.
// Phase 1: block stages hw[g,c] = sum_k W[k]*h[b,g,k,c] into LDS (no shuffles).
// Phase 2: per-wave exp loop over its g-half; 3 shuffles once; LDS combine.
__global__ __launch_bounds__(512) void final_layer_fused(
    const float* __restrict__ x_grid,    // (B, G, C)
    const float* __restrict__ h_grid,    // (B, G, K, C)
    const float* __restrict__ target_x,  // (B, T, C)
    const float* __restrict__ W,         // (1, K)
    const float* __restrict__ bias,      // (1,)
    const float* __restrict__ sigma,     // (K, C)
    float* __restrict__ out)             // (B, T, C)
{
    __shared__ float shw[NGRID * NCH];   // 16 KB: shw[g*8+c]
    __shared__ float lds[8 * 8];         // [wave][c] partials

    const int tid = threadIdx.x;
    const int l   = tid & 63;
    const int w   = tid >> 6;        // 0..7
    const int c   = l & 7;

    const int bi   = blockIdx.x;
    const int b    = bi >> 7;        // 128 tiles per batch
    const int tt   = (bi & 127) * 4; // first target of tile
    const int tl   = w >> 1;         // local target 0..3
    const int t    = tt + tl;
    const int half = w & 1;          // g-half 0/1

    const float LOG2E = 1.4426950408889634f;

    float sg = sigma[l];             // sigma viewed as [k][c] by lane
    float s0 = sigma[c];             // sigma[0][c]
    bool uniform = __all(sg == s0);  // lengthscales uniform across k?

    float tx = target_x[((size_t)b * NTARGET + t) * NCH + c];
    float b0 = bias[0];

    const float* hb = h_grid + (size_t)b * NGRID * 64;
    const size_t bbase = (size_t)b * NGRID * NCH + (size_t)half * (NGRID / 2) * NCH;
    const float* xb = x_grid + bbase;

    float v;
    if (uniform) {
        // ---- Phase 1: stage hw into LDS; 8 values/thread, 8-FMA k-loop ----
        float wk0 = W[0], wk1 = W[1], wk2 = W[2], wk3 = W[3];
        float wk4 = W[4], wk5 = W[5], wk6 = W[6], wk7 = W[7];
#pragma unroll
        for (int vi = 0; vi < 8; ++vi) {
            int f  = tid + vi * 512;          // 0..4095 = g*8 + c
            const float* hp = hb + (size_t)(f >> 3) * 64 + (f & 7);
            float acc;
            acc = wk0 * hp[0];
            acc = fmaf(wk1, hp[8],  acc);
            acc = fmaf(wk2, hp[16], acc);
            acc = fmaf(wk3, hp[24], acc);
            acc = fmaf(wk4, hp[32], acc);
            acc = fmaf(wk5, hp[40], acc);
            acc = fmaf(wk6, hp[48], acc);
            acc = fmaf(wk7, hp[56], acc);
            shw[f] = acc;
        }
        __syncthreads();

        // ---- Phase 2: exp loop; lane-contiguous LDS + global reads ----
        float scale = __expf(s0) + 1e-6f;
        float coef2 = -0.5f * LOG2E / (scale * scale);
        const float* hwb = shw + half * (NGRID / 2) * NCH;

        float a0 = 0.f, a1 = 0.f, a2 = 0.f, a3 = 0.f;
#pragma unroll
        for (int j = 0; j < 32; j += 4) {
            float x0 = xb[64 * (j + 0) + l], h0 = hwb[64 * (j + 0) + l];
            float x1 = xb[64 * (j + 1) + l], h1 = hwb[64 * (j + 1) + l];
            float x2 = xb[64 * (j + 2) + l], h2 = hwb[64 * (j + 2) + l];
            float x3 = xb[64 * (j + 3) + l], h3 = hwb[64 * (j + 3) + l];
            float d0 = x0 - tx, d1 = x1 - tx, d2 = x2 - tx, d3 = x3 - tx;
            a0 = fmaf(h0, EXP2F(coef2 * (d0 * d0)), a0);
            a1 = fmaf(h1, EXP2F(coef2 * (d1 * d1)), a1);
            a2 = fmaf(h2, EXP2F(coef2 * (d2 * d2)), a2);
            a3 = fmaf(h3, EXP2F(coef2 * (d3 * d3)), a3);
        }
        v = (a0 + a1) + (a2 + a3);
    } else {
        // ---- general fallback: per-(k,c) lengthscales, h read directly ----
        float coef2k[NBASIS], wv[NBASIS];
#pragma unroll
        for (int k = 0; k < NBASIS; ++k) {
            float s = __expf(sigma[k * 8 + c]) + 1e-6f;
            coef2k[k] = -0.5f * LOG2E / (s * s);
            wv[k] = W[k];
        }
        const int gs = l >> 3;
        const float* hbh = hb + (size_t)half * (NGRID / 2) * 64;
        float acc = 0.f;
        for (int j = 0; j < 32; ++j) {
            int g = j * 8 + gs;
            float xg = xb[g * 8 + c];
            float d  = xg - tx;
            float d2 = d * d;
#pragma unroll
            for (int k = 0; k < NBASIS; ++k) {
                float hv = hbh[(size_t)g * 64 + k * 8 + c];
                acc = fmaf(wv[k] * hv, EXP2F(coef2k[k] * d2), acc);
            }
        }
        v = acc;
    }

    // reduce over gs (lane bits 3..5) — 3 shuffles once per wave
    v += __shfl_xor(v, 8);
    v += __shfl_xor(v, 16);
    v += __shfl_xor(v, 32);
    if (l < 8) lds[w * 8 + l] = v;
    __syncthreads();

    // combine the two g-halves: 32 threads -> 4 targets x 8 channels
    if (tid < 32) {
        int tl2 = tid >> 3, cc = tid & 7;
        float r = lds[tl2 * 16 + cc] + lds[tl2 * 16 + 8 + cc] + b0;
        out[((size_t)b * NTARGET + (tt + tl2)) * NCH + cc] = r;
    }
}

extern "C" void kernel_launch(void* const* d_in, const int* in_sizes, int n_in,
                              void* d_out, int out_size, void* d_ws, size_t ws_size,
                              hipStream_t stream) {
    const float* x_grid   = (const float*)d_in[0];
    const float* h_grid   = (const float*)d_in[1];
    const float* target_x = (const float*)d_in[2];
    const float* W        = (const float*)d_in[3];
    const float* bias     = (const float*)d_in[4];
    const float* sigma    = (const float*)d_in[5];
    float* out = (float*)d_out;

    final_layer_fused<<<dim3(NB * (NTARGET / 4)), dim3(512), 0, stream>>>(
        x_grid, h_grid, target_x, W, bias, sigma, out);
}